// Round 7
// baseline (392.619 us; speedup 1.0000x reference)
//
#include <hip/hip_runtime.h>
#include <hip/hip_bf16.h>
#include <stdint.h>

typedef __bf16 bf16x8 __attribute__((ext_vector_type(8)));
typedef __bf16 bf16x4 __attribute__((ext_vector_type(4)));
typedef float  f32x4  __attribute__((ext_vector_type(4)));
typedef float  f32x2  __attribute__((ext_vector_type(2)));

#define MFMA16(a,b,c) __builtin_amdgcn_mfma_f32_16x16x32_bf16((a),(b),(c),0,0,0)

static constexpr int H_   = 256;
static constexpr int KEV  = 10;
static constexpr int NTOK = 32 * 4096;

// Pade(5,5) tanh: x*(945+105t+t^2)/(945+420t+15t^2), |err|<7e-4 with clamp.
__device__ __forceinline__ float ptanh(float x){
    float t = x * x;
    float n = fmaf(t, t + 105.0f, 945.0f);
    float d = fmaf(t, fmaf(t, 15.0f, 420.0f), 945.0f);
    float r = x * n * __builtin_amdgcn_rcpf(d);
    return fminf(1.0f, fmaxf(-1.0f, r));
}

__device__ __forceinline__ bf16x8 cvtFrag(const float* p){
    f32x4 a = *(const f32x4*)p;
    f32x4 b = *(const f32x4*)(p + 4);
    bf16x8 r;
    #pragma unroll
    for (int j = 0; j < 4; ++j){ r[j] = (__bf16)a[j]; r[4 + j] = (__bf16)b[j]; }
    return r;
}

// ---- prep 1: v1[j] = sum_k w2[j][256+k]*w1[k]; c1[j] = sum_k w2[j][256+k]*b1[k] + b2[j]
__global__ void prep_vc(const float* __restrict__ w1, const float* __restrict__ b1,
                        const float* __restrict__ w2, const float* __restrict__ b2,
                        float* __restrict__ vc){
    int j = blockIdx.x * 4 + (threadIdx.x >> 6);
    int l = threadIdx.x & 63;
    const float* row = w2 + (size_t)j * (2 * H_) + H_;
    float v = 0.f, cc = 0.f;
    #pragma unroll
    for (int i = 0; i < 4; ++i){
        int k = l + 64 * i;
        float w = row[k];
        v  += w * w1[k];
        cc += w * b1[k];
    }
    #pragma unroll
    for (int off = 32; off; off >>= 1){
        v  += __shfl_down(v,  off, 64);
        cc += __shfl_down(cc, off, 64);
    }
    if (l == 0){ vc[j] = v; vc[H_ + j] = cc + b2[j]; }
}

// ---- prep 2: pack weights to bf16 in MFMA fragment order.
// chunk b (layer b>>4, n0 = b&15): slot = (s*4+q)*16+c holds W[n0*16+c][32s+8q .. +8]
__global__ void prep_pack(const float* __restrict__ w2, const float* __restrict__ wA,
                          const float* __restrict__ wB, __hip_bfloat16* __restrict__ pk){
    int b  = blockIdx.x;
    int L  = b >> 4, n0 = b & 15;
    const float* W = (L == 0) ? w2 : ((L == 1) ? wA : wB);
    int K = (L == 0) ? 2 * H_ : H_;       // layer1 uses first 256 cols of w2
    __hip_bfloat16* dst = pk + (size_t)b * 4096;
    int t = threadIdx.x;
    #pragma unroll
    for (int u = 0; u < 2; ++u){
        int slot = t * 2 + u;
        int s = slot >> 6, q = (slot >> 4) & 3, c = slot & 15;
        const float* src = W + (size_t)(n0 * 16 + c) * K + 32 * s + 8 * q;
        #pragma unroll
        for (int j = 0; j < 8; ++j) dst[slot * 8 + j] = __float2bfloat16(src[j]);
    }
}

// Block-cooperative feature-split: 4 waves x 32 tokens. Wave w owns feats [64w,64w+64)
// for all 32 tokens (2 token groups). Each weight byte read ONCE per block.
// Acts/tangents: 32 KB shared LDS, 5 barriers total (register-preload of fragments
// makes single-buffering safe). Weights: global->VGPR double-buffered.
__global__ __launch_bounds__(256, 2) void chfn_kernel(
    const float* __restrict__ hs, const float* __restrict__ td,
    const __hip_bfloat16* __restrict__ wpk,
    const float* __restrict__ bA, const float* __restrict__ bB,
    const float* __restrict__ w3, const float* __restrict__ b3,
    const float* __restrict__ vc,
    float* __restrict__ out)
{
    __shared__ __hip_bfloat16 sA[32 * H_];     // 16 KB activations (swizzled)
    __shared__ __hip_bfloat16 sD[32 * H_];     // 16 KB tangents

    const int tid  = threadIdx.x;
    const int wave = tid >> 6;
    const int lane = tid & 63;
    const int q    = lane >> 4;
    const int c    = lane & 15;
    const int tb   = blockIdx.x * 32;

    const bf16x8* wp = (const bf16x8*)wpk;
    const int ws = q * 16 + c;                 // lane slot within a weight chunk

    // prefetch first weight chunk (chunk 4*wave) into Wbuf[0]
    bf16x8 Wbuf[2][8];
    {
        const bf16x8* b = wp + (size_t)(4 * wave) * 512 + ws;
        #pragma unroll
        for (int s = 0; s < 8; ++s) Wbuf[0][s] = b[s * 64];
    }

    // h fragments for both token groups (B-operand: lane c = token, k = feat)
    bf16x8 aF[2][8], aB[2][8];
    #pragma unroll
    for (int tg = 0; tg < 2; ++tg){
        const float* h0 = hs + (size_t)(tb + 16 * tg + c) * H_ + 8 * q;
        #pragma unroll
        for (int s = 0; s < 8; ++s) aF[tg][s] = cvtFrag(h0 + 32 * s);
    }
    float tdg[2] = { td[tb + c], td[tb + 16 + c] };

    // ---- layer 1: x = h@w2h^T + td*v1 + c1; act = tanh(x); tangent = (1-act^2)*v1
    #pragma unroll
    for (int n0 = 0; n0 < 4; ++n0){
        bf16x8* cur = Wbuf[n0 & 1];
        bf16x8* nxt = Wbuf[(n0 + 1) & 1];
        {   // prefetch next chunk in this wave's sequence
            int gn = (n0 < 3) ? (4 * wave + n0 + 1) : (16 + 4 * wave);
            const bf16x8* b = wp + (size_t)gn * 512 + ws;
            #pragma unroll
            for (int s = 0; s < 8; ++s) nxt[s] = b[s * 64];
        }
        int fb0 = 64 * wave + 16 * n0;                 // chunk's base feat
        f32x4 v4 = *(const f32x4*)(vc + fb0 + 4 * q);
        f32x4 c4 = *(const f32x4*)(vc + H_ + fb0 + 4 * q);
        int chn = 8 * wave + 2 * n0 + (q >> 1);        // 8-feat chunk index of this lane
        #pragma unroll
        for (int tg = 0; tg < 2; ++tg){
            f32x4 fa = c4;                              // fold c1 into accumulator
            f32x4 fb = {0.f,0.f,0.f,0.f};
            #pragma unroll
            for (int s = 0; s < 4; ++s){
                fa = MFMA16(cur[s],     aF[tg][s],     fa);
                fb = MFMA16(cur[s + 4], aF[tg][s + 4], fb);
            }
            bf16x4 pa, pd;
            #pragma unroll
            for (int r = 0; r < 4; ++r){
                float x  = fmaf(tdg[tg], v4[r], fa[r] + fb[r]);
                float th = ptanh(x);
                float dd = fmaf(-th, th, 1.0f) * v4[r];
                pa[r] = (__bf16)th; pd[r] = (__bf16)dd;
            }
            int row = 16 * tg + c;
            int off = row * H_ + (((chn + row) & 31) << 3) + ((q & 1) << 2);
            *(bf16x4*)((void*)(sA + off)) = pa;
            *(bf16x4*)((void*)(sD + off)) = pd;
        }
    }
    __syncthreads();                                    // barrier 1: L1 acts visible

    // ---- layers 2 & 3
    #pragma unroll 1
    for (int L = 1; L <= 2; ++L){
        const float* bias = (L == 1) ? bA : bB;
        // read phase: preload ALL fragments for this layer (both groups) into regs
        #pragma unroll
        for (int tg = 0; tg < 2; ++tg){
            int row = 16 * tg + c;
            const __hip_bfloat16* a0 = sA + row * H_;
            const __hip_bfloat16* d0 = sD + row * H_;
            #pragma unroll
            for (int s = 0; s < 8; ++s){
                int chn = (((4 * s + q) + row) & 31) << 3;
                aF[tg][s] = *(const bf16x8*)(a0 + chn);
                aB[tg][s] = *(const bf16x8*)(d0 + chn);
            }
        }
        __syncthreads();                                // reads done -> writes may begin
        #pragma unroll
        for (int n0 = 0; n0 < 4; ++n0){
            bf16x8* cur = Wbuf[n0 & 1];
            bf16x8* nxt = Wbuf[(n0 + 1) & 1];
            {
                int gn = (n0 < 3) ? (16 * L + 4 * wave + n0 + 1) : (16 * (L + 1) + 4 * wave);
                if (gn > 47) gn = 47;                   // clamped end reload, harmless
                const bf16x8* b = wp + (size_t)gn * 512 + ws;
                #pragma unroll
                for (int s = 0; s < 8; ++s) nxt[s] = b[s * 64];
            }
            int fb0 = 64 * wave + 16 * n0;
            f32x4 b4 = *(const f32x4*)(bias + fb0 + 4 * q);
            int chn = 8 * wave + 2 * n0 + (q >> 1);
            #pragma unroll
            for (int tg = 0; tg < 2; ++tg){
                f32x4 fa = b4;                          // fold bias into accumulator
                f32x4 fb = {0.f,0.f,0.f,0.f};
                f32x4 ga = {0.f,0.f,0.f,0.f};
                f32x4 gb = {0.f,0.f,0.f,0.f};
                #pragma unroll
                for (int s = 0; s < 4; ++s){
                    fa = MFMA16(cur[s],     aF[tg][s],     fa);
                    ga = MFMA16(cur[s],     aB[tg][s],     ga);
                    fb = MFMA16(cur[s + 4], aF[tg][s + 4], fb);
                    gb = MFMA16(cur[s + 4], aB[tg][s + 4], gb);
                }
                bf16x4 pa, pd;
                #pragma unroll
                for (int r = 0; r < 4; ++r){
                    float th = ptanh(fa[r] + fb[r]);
                    float dd = fmaf(-th, th, 1.0f) * (ga[r] + gb[r]);
                    pa[r] = (__bf16)th; pd[r] = (__bf16)dd;
                }
                int row = 16 * tg + c;
                int off = row * H_ + (((chn + row) & 31) << 3) + ((q & 1) << 2);
                *(bf16x4*)((void*)(sA + off)) = pa;
                *(bf16x4*)((void*)(sD + off)) = pd;
            }
        }
        __syncthreads();                                // writes done -> next reads safe
    }

    // ---- head (K=10): waves 0,1 handle token group tg = wave
    if (wave < 2){
        int row = 16 * wave + c;
        const __hip_bfloat16* a0 = sA + row * H_;
        const __hip_bfloat16* d0 = sD + row * H_;
        #pragma unroll
        for (int s = 0; s < 8; ++s){
            int chn = (((4 * s + q) + row) & 31) << 3;
            aF[0][s] = *(const bf16x8*)(a0 + chn);
            aB[0][s] = *(const bf16x8*)(d0 + chn);
        }
        int crow = (c < KEV) ? c : 0;                   // A-row clamp; rows>=10 never stored
        const float* wp3 = w3 + (size_t)crow * H_ + 8 * q;
        f32x4 fa = {0.f,0.f,0.f,0.f}, fb = {0.f,0.f,0.f,0.f};
        f32x4 ga = {0.f,0.f,0.f,0.f}, gb = {0.f,0.f,0.f,0.f};
        #pragma unroll
        for (int s = 0; s < 4; ++s){
            bf16x8 bv0 = cvtFrag(wp3 + 32 * s);
            bf16x8 bv1 = cvtFrag(wp3 + 32 * (s + 4));
            fa = MFMA16(bv0, aF[0][s],     fa);
            ga = MFMA16(bv0, aB[0][s],     ga);
            fb = MFMA16(bv1, aF[0][s + 4], fb);
            gb = MFMA16(bv1, aB[0][s + 4], gb);
        }
        int fbase = 4 * q;
        size_t token = tb + 16 * wave + c;
        float sp[4], dv[4];
        #pragma unroll
        for (int r = 0; r < 4; ++r){
            int fi   = fbase + r;
            float bn = b3[(fi < KEV) ? fi : (KEV - 1)];
            float z  = (fa[r] + fb[r]) + bn;
            float a  = fabsf(z);
            float e  = __builtin_amdgcn_exp2f(-1.4426950408889634f * a);  // exp(-|z|)
            sp[r] = fmaxf(z, 0.f) + 0.69314718055994531f * __builtin_amdgcn_logf(1.0f + e);
            float sg = __builtin_amdgcn_rcpf(1.0f + e);
            sg = (z >= 0.f) ? sg : 1.0f - sg;                             // sigmoid(z)
            dv[r] = sg * (ga[r] + gb[r]) * (1.0f / 131072.0f);            // /(B*S)
        }
        float* o0 = out + token * KEV + fbase;
        float* o1 = out + (size_t)NTOK * KEV + token * KEV + fbase;
        if (q < 2){
            *(f32x2*)o0       = (f32x2){sp[0], sp[1]};
            *(f32x2*)(o0 + 2) = (f32x2){sp[2], sp[3]};
            *(f32x2*)o1       = (f32x2){dv[0], dv[1]};
            *(f32x2*)(o1 + 2) = (f32x2){dv[2], dv[3]};
        } else if (q == 2){
            *(f32x2*)o0 = (f32x2){sp[0], sp[1]};
            *(f32x2*)o1 = (f32x2){dv[0], dv[1]};
        }
    }
}

extern "C" void kernel_launch(void* const* d_in, const int* in_sizes, int n_in,
                              void* d_out, int out_size, void* d_ws, size_t ws_size,
                              hipStream_t stream){
    const float* hs = (const float*)d_in[0];
    const float* td = (const float*)d_in[1];
    const float* w1 = (const float*)d_in[2];
    const float* b1 = (const float*)d_in[3];
    const float* w2 = (const float*)d_in[4];
    const float* b2 = (const float*)d_in[5];
    const float* wA = (const float*)d_in[6];
    const float* bA = (const float*)d_in[7];
    const float* wB = (const float*)d_in[8];
    const float* bB = (const float*)d_in[9];
    const float* w3 = (const float*)d_in[10];
    const float* b3 = (const float*)d_in[11];

    float*          vc  = (float*)d_ws;                              // 512 fp32
    __hip_bfloat16* wpk = (__hip_bfloat16*)((char*)d_ws + 4096);     // 48*8KB packed weights
    float*          outp = (float*)d_out;

    prep_vc  <<<64, 256, 0, stream>>>(w1, b1, w2, b2, vc);
    prep_pack<<<48, 256, 0, stream>>>(w2, wA, wB, wpk);
    chfn_kernel<<<NTOK / 32, 256, 0, stream>>>(hs, td, wpk, bA, bB, w3, b3, vc, outp);
}

// Round 8
// 330.263 us; speedup vs baseline: 1.1888x; 1.1888x over previous
//
#include <hip/hip_runtime.h>
#include <hip/hip_bf16.h>
#include <stdint.h>

typedef __bf16 bf16x8 __attribute__((ext_vector_type(8)));
typedef __bf16 bf16x4 __attribute__((ext_vector_type(4)));
typedef float  f32x4  __attribute__((ext_vector_type(4)));
typedef float  f32x2  __attribute__((ext_vector_type(2)));

#define MFMA16(a,b,c) __builtin_amdgcn_mfma_f32_16x16x32_bf16((a),(b),(c),0,0,0)

static constexpr int H_   = 256;
static constexpr int KEV  = 10;
static constexpr int NTOK = 32 * 4096;

// Pade(5,5) tanh with med3 clamp: |err|<7e-4.
__device__ __forceinline__ float ptanh(float x){
    float t = x * x;
    float n = fmaf(t, t + 105.0f, 945.0f);
    float d = fmaf(t, fmaf(t, 15.0f, 420.0f), 945.0f);
    float r = x * n * __builtin_amdgcn_rcpf(d);
    return __builtin_amdgcn_fmed3f(r, -1.0f, 1.0f);
}

__device__ __forceinline__ bf16x8 cvtFrag(const float* p){
    f32x4 a = *(const f32x4*)p;
    f32x4 b = *(const f32x4*)(p + 4);
    bf16x8 r;
    #pragma unroll
    for (int j = 0; j < 4; ++j){ r[j] = (__bf16)a[j]; r[4 + j] = (__bf16)b[j]; }
    return r;
}

// ---- prep 1: v1 | c1 | b3-padded into vc[0..527]
__global__ void prep_vc(const float* __restrict__ w1, const float* __restrict__ b1,
                        const float* __restrict__ w2, const float* __restrict__ b2,
                        const float* __restrict__ b3, float* __restrict__ vc){
    int j = blockIdx.x * 4 + (threadIdx.x >> 6);
    int l = threadIdx.x & 63;
    const float* row = w2 + (size_t)j * (2 * H_) + H_;
    float v = 0.f, cc = 0.f;
    #pragma unroll
    for (int i = 0; i < 4; ++i){
        int k = l + 64 * i;
        float w = row[k];
        v  += w * w1[k];
        cc += w * b1[k];
    }
    #pragma unroll
    for (int off = 32; off; off >>= 1){
        v  += __shfl_down(v,  off, 64);
        cc += __shfl_down(cc, off, 64);
    }
    if (l == 0){ vc[j] = v; vc[H_ + j] = cc + b2[j]; }
    if (blockIdx.x == 0 && threadIdx.x < 16)
        vc[2 * H_ + threadIdx.x] = (threadIdx.x < KEV) ? b3[threadIdx.x] : 0.0f;
}

// ---- prep 2: pack weights (incl. head) to bf16 MFMA fragment order.
// chunk b: layers 0..2 -> b in [0,48), head w3 -> b = 48 (rows >= 10 zeroed).
// slot = (s*4+q)*16+c holds W[row = n0*16+c][32s+8q .. +8]
__global__ void prep_pack(const float* __restrict__ w2, const float* __restrict__ wA,
                          const float* __restrict__ wB, const float* __restrict__ w3,
                          __hip_bfloat16* __restrict__ pk){
    int b  = blockIdx.x;                  // 49 chunks
    int L  = b >> 4, n0 = b & 15;
    const float* W; int K, nrows;
    if (b == 48){ W = w3; K = H_; nrows = KEV; }
    else { W = (L == 0) ? w2 : ((L == 1) ? wA : wB); K = (L == 0) ? 2 * H_ : H_; nrows = 16; }
    __hip_bfloat16* dst = pk + (size_t)b * 4096;
    int t = threadIdx.x;
    #pragma unroll
    for (int u = 0; u < 2; ++u){
        int slot = t * 2 + u;
        int s = slot >> 6, q = (slot >> 4) & 3, c = slot & 15;
        int rr = (b == 48) ? c : (n0 * 16 + c);
        if (c < nrows){
            const float* src = W + (size_t)rr * K + 32 * s + 8 * q;
            #pragma unroll
            for (int j = 0; j < 8; ++j) dst[slot * 8 + j] = __float2bfloat16(src[j]);
        } else {
            #pragma unroll
            for (int j = 0; j < 8; ++j) dst[slot * 8 + j] = __float2bfloat16(0.0f);
        }
    }
}

// Token-ownership, barrier-free. 2 waves x 16 tokens per block; 32 KB LDS/block
// -> 5 blocks/CU = 10 waves/CU. Weights stream global->VGPR double-buffered
// (49 chunks incl. head). VGPR target <=170 for 3 waves/SIMD.
__global__ __launch_bounds__(128, 3) void chfn_kernel(
    const float* __restrict__ hs, const float* __restrict__ td,
    const __hip_bfloat16* __restrict__ wpk,
    const float* __restrict__ bA, const float* __restrict__ bB,
    const float* __restrict__ vc,
    float* __restrict__ out)
{
    __shared__ __hip_bfloat16 sA[2 * 16 * H_];     // 16 KB activations (swizzled)
    __shared__ __hip_bfloat16 sD[2 * 16 * H_];     // 16 KB tangents

    const int tid  = threadIdx.x;
    const int wave = tid >> 6;
    const int lane = tid & 63;
    const int q    = lane >> 4;
    const int c    = lane & 15;
    const int tb   = blockIdx.x * 32 + wave * 16;
    const int wrow = wave * 16;

    const bf16x8* wp = (const bf16x8*)wpk;
    const int ws = q * 16 + c;                     // lane slot within a weight chunk

    // prefetch weight chunk 0
    bf16x8 W0[8], W1[8];
    {
        const bf16x8* b = wp + ws;
        #pragma unroll
        for (int s = 0; s < 8; ++s) W0[s] = b[s * 64];
    }

    // h fragments (fp32 -> bf16, one-time)
    bf16x8 aF[8], aB[8];
    {
        const float* h0 = hs + (size_t)(tb + c) * H_ + 8 * q;
        #pragma unroll
        for (int s = 0; s < 8; ++s) aF[s] = cvtFrag(h0 + 32 * s);
    }
    float myTd = td[tb + c];

    // ---- layer 1: x = h@w2h^T + td*v1 + c1; act = tanh(x); tangent = (1-act^2)*v1
    #pragma unroll 2
    for (int n0 = 0; n0 < 16; ++n0){
        bf16x8* cur = (n0 & 1) ? W1 : W0;
        bf16x8* nxt = (n0 & 1) ? W0 : W1;
        {   // prefetch chunk n0+1
            const bf16x8* b = wp + (size_t)(n0 + 1) * 512 + ws;
            #pragma unroll
            for (int s = 0; s < 8; ++s) nxt[s] = b[s * 64];
        }
        f32x4 v4 = *(const f32x4*)(vc + n0 * 16 + 4 * q);
        f32x4 c4 = *(const f32x4*)(vc + H_ + n0 * 16 + 4 * q);
        f32x4 fa = c4;
        f32x4 fb = {0.f,0.f,0.f,0.f};
        #pragma unroll
        for (int s = 0; s < 4; ++s){
            fa = MFMA16(cur[s],     aF[s],     fa);
            fb = MFMA16(cur[s + 4], aF[s + 4], fb);
        }
        bf16x4 pa, pd;
        #pragma unroll
        for (int r = 0; r < 4; ++r){
            float x  = fmaf(myTd, v4[r], fa[r] + fb[r]);
            float th = ptanh(x);
            float dd = fmaf(-th, th, 1.0f) * v4[r];
            pa[r] = (__bf16)th; pd[r] = (__bf16)dd;
        }
        int chn = 2 * n0 + (q >> 1);
        int off = (wrow + c) * H_ + (((chn + 4 * c) & 31) << 3) + ((q & 1) << 2);
        *(bf16x4*)((void*)(sA + off)) = pa;
        *(bf16x4*)((void*)(sD + off)) = pd;
    }

    // ---- layers 2 & 3 (no barriers: acts are wave-private)
    #pragma unroll 1
    for (int L = 0; L < 2; ++L){
        const float* bias = L ? bB : bA;
        {   // reload act/tangent fragments (chunk chn=4s+q, slot=(chn+4c)&31)
            const __hip_bfloat16* a0 = sA + (wrow + c) * H_;
            const __hip_bfloat16* d0 = sD + (wrow + c) * H_;
            #pragma unroll
            for (int s = 0; s < 8; ++s){
                int chn = (((4 * s + q) + 4 * c) & 31) << 3;
                aF[s] = *(const bf16x8*)(a0 + chn);
                aB[s] = *(const bf16x8*)(d0 + chn);
            }
        }
        #pragma unroll 2
        for (int n0 = 0; n0 < 16; ++n0){
            int g = 16 * (L + 1) + n0;
            bf16x8* cur = (n0 & 1) ? W1 : W0;
            bf16x8* nxt = (n0 & 1) ? W0 : W1;
            {   // prefetch next chunk (g+1 <= 48 always here)
                const bf16x8* b = wp + (size_t)(g + 1) * 512 + ws;
                #pragma unroll
                for (int s = 0; s < 8; ++s) nxt[s] = b[s * 64];
            }
            f32x4 b4 = *(const f32x4*)(bias + n0 * 16 + 4 * q);
            f32x4 fa = b4;
            f32x4 fb = {0.f,0.f,0.f,0.f};
            f32x4 ga = {0.f,0.f,0.f,0.f};
            f32x4 gb = {0.f,0.f,0.f,0.f};
            #pragma unroll
            for (int s = 0; s < 4; ++s){
                fa = MFMA16(cur[s],     aF[s],     fa);
                ga = MFMA16(cur[s],     aB[s],     ga);
                fb = MFMA16(cur[s + 4], aF[s + 4], fb);
                gb = MFMA16(cur[s + 4], aB[s + 4], gb);
            }
            bf16x4 pa, pd;
            #pragma unroll
            for (int r = 0; r < 4; ++r){
                float th = ptanh(fa[r] + fb[r]);
                float dd = fmaf(-th, th, 1.0f) * (ga[r] + gb[r]);
                pa[r] = (__bf16)th; pd[r] = (__bf16)dd;
            }
            int chn = 2 * n0 + (q >> 1);
            int off = (wrow + c) * H_ + (((chn + 4 * c) & 31) << 3) + ((q & 1) << 2);
            *(bf16x4*)((void*)(sA + off)) = pa;
            *(bf16x4*)((void*)(sD + off)) = pd;
        }
    }

    // ---- head: chunk 48 (w3 packed, rows>=10 zero), b3 from vc[512..]
    {
        const __hip_bfloat16* a0 = sA + (wrow + c) * H_;
        const __hip_bfloat16* d0 = sD + (wrow + c) * H_;
        #pragma unroll
        for (int s = 0; s < 8; ++s){
            int chn = (((4 * s + q) + 4 * c) & 31) << 3;
            aF[s] = *(const bf16x8*)(a0 + chn);
            aB[s] = *(const bf16x8*)(d0 + chn);
        }
        bf16x8* cur = W0;                           // chunk 48 parity: 48&1==0
        f32x4 b4 = *(const f32x4*)(vc + 2 * H_ + 4 * q);
        f32x4 fa = b4;
        f32x4 fb = {0.f,0.f,0.f,0.f};
        f32x4 ga = {0.f,0.f,0.f,0.f};
        f32x4 gb = {0.f,0.f,0.f,0.f};
        #pragma unroll
        for (int s = 0; s < 4; ++s){
            fa = MFMA16(cur[s],     aF[s],     fa);
            ga = MFMA16(cur[s],     aB[s],     ga);
            fb = MFMA16(cur[s + 4], aF[s + 4], fb);
            gb = MFMA16(cur[s + 4], aB[s + 4], gb);
        }
        int fbase = 4 * q;
        size_t token = tb + c;
        float sp[4], dv[4];
        #pragma unroll
        for (int r = 0; r < 4; ++r){
            float z  = fa[r] + fb[r];
            float a  = fabsf(z);
            float e  = __builtin_amdgcn_exp2f(-1.4426950408889634f * a);  // exp(-|z|)
            sp[r] = fmaxf(z, 0.f) + 0.69314718055994531f * __builtin_amdgcn_logf(1.0f + e);
            float sg = __builtin_amdgcn_rcpf(1.0f + e);
            sg = (z >= 0.f) ? sg : 1.0f - sg;                             // sigmoid(z)
            dv[r] = sg * (ga[r] + gb[r]) * (1.0f / 131072.0f);            // /(B*S)
        }
        float* o0 = out + token * KEV + fbase;
        float* o1 = out + (size_t)NTOK * KEV + token * KEV + fbase;
        if (q < 2){
            *(f32x2*)o0       = (f32x2){sp[0], sp[1]};
            *(f32x2*)(o0 + 2) = (f32x2){sp[2], sp[3]};
            *(f32x2*)o1       = (f32x2){dv[0], dv[1]};
            *(f32x2*)(o1 + 2) = (f32x2){dv[2], dv[3]};
        } else if (q == 2){
            *(f32x2*)o0 = (f32x2){sp[0], sp[1]};
            *(f32x2*)o1 = (f32x2){dv[0], dv[1]};
        }
    }
}

extern "C" void kernel_launch(void* const* d_in, const int* in_sizes, int n_in,
                              void* d_out, int out_size, void* d_ws, size_t ws_size,
                              hipStream_t stream){
    const float* hs = (const float*)d_in[0];
    const float* td = (const float*)d_in[1];
    const float* w1 = (const float*)d_in[2];
    const float* b1 = (const float*)d_in[3];
    const float* w2 = (const float*)d_in[4];
    const float* b2 = (const float*)d_in[5];
    const float* wA = (const float*)d_in[6];
    const float* bA = (const float*)d_in[7];
    const float* wB = (const float*)d_in[8];
    const float* bB = (const float*)d_in[9];
    const float* w3 = (const float*)d_in[10];
    const float* b3 = (const float*)d_in[11];

    float*          vc  = (float*)d_ws;                              // 528 fp32
    __hip_bfloat16* wpk = (__hip_bfloat16*)((char*)d_ws + 4096);     // 49*8KB packed weights
    float*          outp = (float*)d_out;

    prep_vc  <<<64, 256, 0, stream>>>(w1, b1, w2, b2, b3, vc);
    prep_pack<<<49, 256, 0, stream>>>(w2, wA, wB, w3, wpk);
    chfn_kernel<<<NTOK / 32, 128, 0, stream>>>(hs, td, wpk, bA, bB, vc, outp);
}